// Round 9
// baseline (229.567 us; speedup 1.0000x reference)
//
#include <hip/hip_runtime.h>

// ContrastiveLoss: ys [4096,2048] f32, labels [4096] i32 -> scalar f32
// loss = mean over strict lower triangle of: same ? relu(2-cos)^2 : cos^2
// cos = pairwise cosine similarity of rows of ys (norm clamped at 1e-6).
//
// Round-9: counted-vmcnt double-buffer pipeline (T3-min + T4). 128x128
// tiles (528 blocks, 2.06/CU all-resident at 64KB dbuf LDS), 4 waves of
// 64x64 (halved LDS traffic vs r6), fp8 staging, MX-scaled K=128 MFMA.
// Key: raw s_barrier + s_waitcnt vmcnt(8) -- next tile's loads stay in
// flight across barriers; never vmcnt(0) in the main loop (r3's dbuf
// failed because __syncthreads drains vmcnt(0)).

#define ROWS 4096
#define KDIM 2048
// 128x128 tiles over lower triangle incl. diagonal: 32*33/2 = 528 jobs.
#define NJOBS 528
#define BK 128          // k-elements (= bytes) per K-step
#define NSTEPS (KDIM / BK)  // 16
#define FSCALE 32.0f    // fp8 pre-scale
#define FSCALE2_INV (1.0f / (FSCALE * FSCALE))
#define SCALE_ONE 0x7F7F7F7F  // E8M0 exponent 127 -> 2^0 in every byte

typedef float f32x4 __attribute__((ext_vector_type(4)));
typedef int i32x4 __attribute__((ext_vector_type(4)));
typedef int i32x8 __attribute__((ext_vector_type(8)));

__device__ __forceinline__ void async_copy16(const unsigned char* g, unsigned char* l) {
    __builtin_amdgcn_global_load_lds(
        (const __attribute__((address_space(1))) void*)g,
        (__attribute__((address_space(3))) void*)l,
        16, 0, 0);
}

// ---------------- Kernel 1: row normalize, f32 -> fp8 e4m3 (x32) ----------
__global__ __launch_bounds__(256) void normalize_rows(
    const float* __restrict__ ys, unsigned int* __restrict__ yn) {
    int row = blockIdx.x;
    const float4* src = (const float4*)(ys + (size_t)row * KDIM);
    float4 vals[2];
    float ss = 0.f;
#pragma unroll
    for (int i = 0; i < 2; ++i) {
        float4 v = src[threadIdx.x + i * 256];
        vals[i] = v;
        ss += v.x * v.x + v.y * v.y + v.z * v.z + v.w * v.w;
    }
#pragma unroll
    for (int off = 32; off > 0; off >>= 1) ss += __shfl_down(ss, off);
    __shared__ float red[4];
    int lane = threadIdx.x & 63, wv = threadIdx.x >> 6;
    if (lane == 0) red[wv] = ss;
    __syncthreads();
    float tot = red[0] + red[1] + red[2] + red[3];
    float inv = FSCALE / fmaxf(sqrtf(tot), 1e-6f);
    unsigned int* dst = yn + (size_t)row * (KDIM / 4);
#pragma unroll
    for (int i = 0; i < 2; ++i) {
        float4 v = vals[i];
        int p = __builtin_amdgcn_cvt_pk_fp8_f32(v.x * inv, v.y * inv, 0, false);
        p = __builtin_amdgcn_cvt_pk_fp8_f32(v.z * inv, v.w * inv, p, true);
        dst[threadIdx.x + i * 256] = (unsigned int)p;
    }
}

// ---------------- Kernel 2: 128x128 Gram tile + fused loss ----------------
__device__ __forceinline__ void stage_tile(
    const unsigned char* __restrict__ yn, int rowA, int rowB, int k0,
    unsigned char* As, unsigned char* Bs, int wv, int srow, int sbyte) {
    // 32 chunks of 8 rows x 128 fp8 (1KB): 0..15 -> A, 16..31 -> B.
    // 8 chunks per wave -> per-wave vmcnt granularity is 8.
#pragma unroll
    for (int it = 0; it < 8; ++it) {
        int chunk = it * 4 + wv;
        if (chunk < 16) {
            int rr = chunk * 8 + srow;
            async_copy16(yn + (size_t)(rowA + rr) * KDIM + k0 + sbyte,
                         As + chunk * 1024);
        } else {
            int c2 = chunk - 16;
            int rr = c2 * 8 + srow;
            async_copy16(yn + (size_t)(rowB + rr) * KDIM + k0 + sbyte,
                         Bs + c2 * 1024);
        }
    }
}

__device__ __forceinline__ void compute_step(
    const unsigned char* As, const unsigned char* Bs,
    f32x4 acc[4][4], int wr, int wc, int colB, int kq) {
    // Lane kq's 32 true-k bytes sit at granules 2kq, 2kq+1; staging's
    // inverse-XOR means addr0 and addr0^16 give ascending k order.
    i32x8 af8[4];
#pragma unroll
    for (int m = 0; m < 4; ++m) {
        int row = wr * 64 + m * 16 + colB;
        int byte0 = (row * BK + kq * 32) ^ ((row & 7) << 4);
        i32x4 lo = *(const i32x4*)(As + byte0);
        i32x4 hi = *(const i32x4*)(As + (byte0 ^ 16));
        af8[m] = (i32x8){lo.x, lo.y, lo.z, lo.w, hi.x, hi.y, hi.z, hi.w};
    }
#pragma unroll
    for (int n = 0; n < 4; ++n) {
        int row = wc * 64 + n * 16 + colB;
        int byte0 = (row * BK + kq * 32) ^ ((row & 7) << 4);
        i32x4 lo = *(const i32x4*)(Bs + byte0);
        i32x4 hi = *(const i32x4*)(Bs + (byte0 ^ 16));
        i32x8 bn = (i32x8){lo.x, lo.y, lo.z, lo.w, hi.x, hi.y, hi.z, hi.w};
#pragma unroll
        for (int m = 0; m < 4; ++m)
            acc[m][n] = __builtin_amdgcn_mfma_scale_f32_16x16x128_f8f6f4(
                af8[m], bn, acc[m][n],
                0, 0,                  // cbsz=fp8, blgp=fp8
                0, SCALE_ONE,          // opsel_a, scale_a (1.0)
                0, SCALE_ONE);         // opsel_b, scale_b (1.0)
    }
}

__global__ __launch_bounds__(256) void gram_loss(
    const unsigned char* __restrict__ yn, const int* __restrict__ labels,
    float* __restrict__ partials) {
    // XCD-chunk swizzle (bijective: 528 % 8 == 0, 66 jobs per XCD):
    int t = (blockIdx.x & 7) * (NJOBS / 8) + (blockIdx.x >> 3);
    // job t -> (bi, bj): jobs for bi occupy [bi(bi+1)/2, (bi+1)(bi+2)/2)
    int bi = (int)((sqrtf(8.0f * t + 1.0f) - 1.0f) * 0.5f);
    while (bi * (bi + 1) / 2 > t) --bi;
    while ((bi + 1) * (bi + 2) / 2 <= t) ++bi;
    int bj = t - bi * (bi + 1) / 2;

    __shared__ __attribute__((aligned(16))) unsigned char As[2][128 * BK];  // 2x16KB
    __shared__ __attribute__((aligned(16))) unsigned char Bs[2][128 * BK];  // 2x16KB
    __shared__ int labI[128];
    __shared__ int labJ[128];
    __shared__ float red[4];

    int tid = threadIdx.x, lane = tid & 63, wv = tid >> 6;
    int wr = wv >> 1, wc = wv & 1;
    int rowA = bi * 128, rowB = bj * 128;

    if (tid < 128) labI[tid] = labels[rowA + tid];
    else labJ[tid - 128] = labels[rowB + tid - 128];

    // staging: lane covers row lane>>3; 16B granule (lane&7) pre-XORed with
    // row so the linear global_load_lds writes land swizzled: byte^=((row&7)<<4).
    int srow = lane >> 3;
    int sbyte = ((lane & 7) ^ srow) * 16;

    f32x4 zero = {0.f, 0.f, 0.f, 0.f};
    f32x4 acc[4][4];
#pragma unroll
    for (int m = 0; m < 4; ++m)
#pragma unroll
        for (int n = 0; n < 4; ++n) acc[m][n] = zero;

    int colB = lane & 15;  // spatial index within 16x16 fragment
    int kq = lane >> 4;    // k-quarter: lane holds k = 32*kq .. +31

    // ---- counted-vmcnt double-buffer pipeline (16 K-steps) ----
    stage_tile(yn, rowA, rowB, 0 * BK, As[0], Bs[0], wv, srow, sbyte);
    stage_tile(yn, rowA, rowB, 1 * BK, As[1], Bs[1], wv, srow, sbyte);
    asm volatile("s_waitcnt vmcnt(8) lgkmcnt(0)" ::: "memory");  // tile0 + labels
    __builtin_amdgcn_s_barrier();

#pragma unroll
    for (int ts = 0; ts < NSTEPS - 2; ts += 2) {
        compute_step(As[0], Bs[0], acc, wr, wc, colB, kq);   // tile ts
        __builtin_amdgcn_s_barrier();                         // buf0 free
        stage_tile(yn, rowA, rowB, (ts + 2) * BK, As[0], Bs[0], wv, srow, sbyte);
        asm volatile("s_waitcnt vmcnt(8)" ::: "memory");      // tile ts+1 landed
        __builtin_amdgcn_s_barrier();

        compute_step(As[1], Bs[1], acc, wr, wc, colB, kq);   // tile ts+1
        __builtin_amdgcn_s_barrier();                         // buf1 free
        stage_tile(yn, rowA, rowB, (ts + 3) * BK, As[1], Bs[1], wv, srow, sbyte);
        asm volatile("s_waitcnt vmcnt(8)" ::: "memory");      // tile ts+2 landed
        __builtin_amdgcn_s_barrier();
    }
    compute_step(As[0], Bs[0], acc, wr, wc, colB, kq);       // tile 14
    __builtin_amdgcn_s_barrier();
    asm volatile("s_waitcnt vmcnt(0)" ::: "memory");          // tile 15 landed
    __builtin_amdgcn_s_barrier();
    compute_step(As[1], Bs[1], acc, wr, wc, colB, kq);       // tile 15

    // fused loss epilogue: ti = wr*64+m*16+kq*4+j, tj = wc*64+n*16+colB
    float lsum = 0.f;
#pragma unroll
    for (int m = 0; m < 4; ++m) {
#pragma unroll
        for (int n = 0; n < 4; ++n) {
#pragma unroll
            for (int j = 0; j < 4; ++j) {
                int ti = wr * 64 + m * 16 + kq * 4 + j;
                int tj = wc * 64 + n * 16 + colB;
                int gi = rowA + ti, gj = rowB + tj;
                if (gi > gj) {
                    float c = acc[m][n][j] * FSCALE2_INV;
                    float v = (labI[ti] == labJ[tj]) ? fmaxf(2.0f - c, 0.0f) : c;
                    lsum += v * v;
                }
            }
        }
    }
#pragma unroll
    for (int off = 32; off > 0; off >>= 1) lsum += __shfl_down(lsum, off);
    if (lane == 0) red[wv] = lsum;
    __syncthreads();
    if (tid == 0) partials[blockIdx.x] = red[0] + red[1] + red[2] + red[3];
}

// ---------------- Kernel 3: deterministic final reduction -----------------
__global__ __launch_bounds__(256) void finalize(
    const float* __restrict__ partials, float* __restrict__ out) {
    float s = 0.f;
    for (int i = threadIdx.x; i < NJOBS; i += 256) s += partials[i];
#pragma unroll
    for (int off = 32; off > 0; off >>= 1) s += __shfl_down(s, off);
    __shared__ float red[4];
    int lane = threadIdx.x & 63, wv = threadIdx.x >> 6;
    if (lane == 0) red[wv] = s;
    __syncthreads();
    if (threadIdx.x == 0) {
        const double npair = (double)ROWS * (ROWS - 1) / 2.0;
        out[0] = (float)((double)(red[0] + red[1] + red[2] + red[3]) / npair);
    }
}

extern "C" void kernel_launch(void* const* d_in, const int* in_sizes, int n_in,
                              void* d_out, int out_size, void* d_ws, size_t ws_size,
                              hipStream_t stream) {
    const float* ys = (const float*)d_in[0];
    const int* labels = (const int*)d_in[1];
    float* out = (float*)d_out;

    unsigned char* yn = (unsigned char*)d_ws;                        // 8 MB fp8
    float* partials = (float*)((char*)d_ws + (size_t)ROWS * KDIM);   // 2.1 KB

    normalize_rows<<<ROWS, 256, 0, stream>>>(ys, (unsigned int*)yn);
    gram_loss<<<NJOBS, 256, 0, stream>>>(yn, labels, partials);
    finalize<<<1, 256, 0, stream>>>(partials, out);
}

// Round 10
// 50.795 us; speedup vs baseline: 4.5195x; 4.5195x over previous
//
#include <hip/hip_runtime.h>

// ContrastiveLoss: ys [4096,2048] f32, labels [4096] i32 -> scalar f32
// loss = mean over strict lower triangle of: same ? relu(2-cos)^2 : cos^2
// cos = pairwise cosine similarity of rows of ys (norm clamped at 1e-6).
//
// Round-10: round-9 counted-vmcnt dbuf pipeline with the register blowup
// fixed: `#pragma unroll 1` on the main loop (r9's full unroll spilled:
// VGPR=256, 270MB scratch writes) and precomputed per-wave staging base
// pointers. 128x128 tiles (528 blocks all-resident), 4 waves of 64x64,
// fp8 staging, MX-scaled K=128 MFMA, s_waitcnt vmcnt(8) + raw s_barrier.

#define ROWS 4096
#define KDIM 2048
// 128x128 tiles over lower triangle incl. diagonal: 32*33/2 = 528 jobs.
#define NJOBS 528
#define BK 128              // k-elements (= bytes) per K-step
#define NSTEPS (KDIM / BK)  // 16
#define FSCALE 32.0f        // fp8 pre-scale
#define FSCALE2_INV (1.0f / (FSCALE * FSCALE))
#define SCALE_ONE 0x7F7F7F7F  // E8M0 exponent 127 -> 2^0 in every byte

typedef float f32x4 __attribute__((ext_vector_type(4)));
typedef int i32x4 __attribute__((ext_vector_type(4)));
typedef int i32x8 __attribute__((ext_vector_type(8)));

__device__ __forceinline__ void async_copy16(const unsigned char* g, unsigned char* l) {
    __builtin_amdgcn_global_load_lds(
        (const __attribute__((address_space(1))) void*)g,
        (__attribute__((address_space(3))) void*)l,
        16, 0, 0);
}

// ---------------- Kernel 1: row normalize, f32 -> fp8 e4m3 (x32) ----------
__global__ __launch_bounds__(256) void normalize_rows(
    const float* __restrict__ ys, unsigned int* __restrict__ yn) {
    int row = blockIdx.x;
    const float4* src = (const float4*)(ys + (size_t)row * KDIM);
    float4 vals[2];
    float ss = 0.f;
#pragma unroll
    for (int i = 0; i < 2; ++i) {
        float4 v = src[threadIdx.x + i * 256];
        vals[i] = v;
        ss += v.x * v.x + v.y * v.y + v.z * v.z + v.w * v.w;
    }
#pragma unroll
    for (int off = 32; off > 0; off >>= 1) ss += __shfl_down(ss, off);
    __shared__ float red[4];
    int lane = threadIdx.x & 63, wv = threadIdx.x >> 6;
    if (lane == 0) red[wv] = ss;
    __syncthreads();
    float tot = red[0] + red[1] + red[2] + red[3];
    float inv = FSCALE / fmaxf(sqrtf(tot), 1e-6f);
    unsigned int* dst = yn + (size_t)row * (KDIM / 4);
#pragma unroll
    for (int i = 0; i < 2; ++i) {
        float4 v = vals[i];
        int p = __builtin_amdgcn_cvt_pk_fp8_f32(v.x * inv, v.y * inv, 0, false);
        p = __builtin_amdgcn_cvt_pk_fp8_f32(v.z * inv, v.w * inv, p, true);
        dst[threadIdx.x + i * 256] = (unsigned int)p;
    }
}

// ---------------- Kernel 2: 128x128 Gram tile + fused loss ----------------
// Per-wave staging: wave wv covers chunks {it*4+wv}; A-chunk rows step by
// 32 per it, so two base pointers + immediate strides suffice.
__device__ __forceinline__ void stage_tile(
    const unsigned char* pA, const unsigned char* pB, int k0,
    unsigned char* As, unsigned char* Bs, int wv) {
#pragma unroll
    for (int it = 0; it < 4; ++it)
        async_copy16(pA + (size_t)it * 32 * KDIM + k0, As + (it * 4 + wv) * 1024);
#pragma unroll
    for (int it = 0; it < 4; ++it)
        async_copy16(pB + (size_t)it * 32 * KDIM + k0, Bs + (it * 4 + wv) * 1024);
}

__device__ __forceinline__ void compute_step(
    const unsigned char* As, const unsigned char* Bs,
    f32x4 acc[4][4], int wr, int wc, int colB, int kq) {
    // Lane kq's 32 true-k bytes sit at granules 2kq, 2kq+1; staging's
    // inverse-XOR means addr0 and addr0^16 give ascending k order.
    i32x8 af8[4];
#pragma unroll
    for (int m = 0; m < 4; ++m) {
        int row = wr * 64 + m * 16 + colB;
        int byte0 = (row * BK + kq * 32) ^ ((row & 7) << 4);
        i32x4 lo = *(const i32x4*)(As + byte0);
        i32x4 hi = *(const i32x4*)(As + (byte0 ^ 16));
        af8[m] = (i32x8){lo.x, lo.y, lo.z, lo.w, hi.x, hi.y, hi.z, hi.w};
    }
#pragma unroll
    for (int n = 0; n < 4; ++n) {
        int row = wc * 64 + n * 16 + colB;
        int byte0 = (row * BK + kq * 32) ^ ((row & 7) << 4);
        i32x4 lo = *(const i32x4*)(Bs + byte0);
        i32x4 hi = *(const i32x4*)(Bs + (byte0 ^ 16));
        i32x8 bn = (i32x8){lo.x, lo.y, lo.z, lo.w, hi.x, hi.y, hi.z, hi.w};
#pragma unroll
        for (int m = 0; m < 4; ++m)
            acc[m][n] = __builtin_amdgcn_mfma_scale_f32_16x16x128_f8f6f4(
                af8[m], bn, acc[m][n],
                0, 0,                  // cbsz=fp8, blgp=fp8
                0, SCALE_ONE,          // opsel_a, scale_a (1.0)
                0, SCALE_ONE);         // opsel_b, scale_b (1.0)
    }
}

__global__ __launch_bounds__(256) void gram_loss(
    const unsigned char* __restrict__ yn, const int* __restrict__ labels,
    float* __restrict__ partials) {
    // XCD-chunk swizzle (bijective: 528 % 8 == 0, 66 jobs per XCD):
    int t = (blockIdx.x & 7) * (NJOBS / 8) + (blockIdx.x >> 3);
    // job t -> (bi, bj): jobs for bi occupy [bi(bi+1)/2, (bi+1)(bi+2)/2)
    int bi = (int)((sqrtf(8.0f * t + 1.0f) - 1.0f) * 0.5f);
    while (bi * (bi + 1) / 2 > t) --bi;
    while ((bi + 1) * (bi + 2) / 2 <= t) ++bi;
    int bj = t - bi * (bi + 1) / 2;

    __shared__ __attribute__((aligned(16))) unsigned char As[2][128 * BK];  // 2x16KB
    __shared__ __attribute__((aligned(16))) unsigned char Bs[2][128 * BK];  // 2x16KB
    __shared__ int labI[128];
    __shared__ int labJ[128];
    __shared__ float red[4];

    int tid = threadIdx.x, lane = tid & 63, wv = tid >> 6;
    int wr = wv >> 1, wc = wv & 1;
    int rowA = bi * 128, rowB = bj * 128;

    if (tid < 128) labI[tid] = labels[rowA + tid];
    else labJ[tid - 128] = labels[rowB + tid - 128];

    // staging: lane covers row lane>>3; 16B granule (lane&7) pre-XORed with
    // row so linear global_load_lds writes land swizzled: byte^=((row&7)<<4).
    int srow = lane >> 3;
    int sbyte = ((lane & 7) ^ srow) * 16;
    const unsigned char* pA = yn + (size_t)(rowA + wv * 8 + srow) * KDIM + sbyte;
    const unsigned char* pB = yn + (size_t)(rowB + wv * 8 + srow) * KDIM + sbyte;

    f32x4 zero = {0.f, 0.f, 0.f, 0.f};
    f32x4 acc[4][4];
#pragma unroll
    for (int m = 0; m < 4; ++m)
#pragma unroll
        for (int n = 0; n < 4; ++n) acc[m][n] = zero;

    int colB = lane & 15;  // spatial index within 16x16 fragment
    int kq = lane >> 4;    // k-quarter: lane holds k = 32*kq .. +31

    // ---- counted-vmcnt double-buffer pipeline (16 K-steps) ----
    stage_tile(pA, pB, 0 * BK, As[0], Bs[0], wv);
    stage_tile(pA, pB, 1 * BK, As[1], Bs[1], wv);
    asm volatile("s_waitcnt vmcnt(8) lgkmcnt(0)" ::: "memory");  // tile0 + labels
    __builtin_amdgcn_s_barrier();

#pragma unroll 1
    for (int ts = 0; ts < NSTEPS - 2; ts += 2) {
        compute_step(As[0], Bs[0], acc, wr, wc, colB, kq);   // tile ts
        __builtin_amdgcn_s_barrier();                         // buf0 free
        stage_tile(pA, pB, (ts + 2) * BK, As[0], Bs[0], wv);
        asm volatile("s_waitcnt vmcnt(8)" ::: "memory");      // tile ts+1 landed
        __builtin_amdgcn_s_barrier();

        compute_step(As[1], Bs[1], acc, wr, wc, colB, kq);   // tile ts+1
        __builtin_amdgcn_s_barrier();                         // buf1 free
        stage_tile(pA, pB, (ts + 3) * BK, As[1], Bs[1], wv);
        asm volatile("s_waitcnt vmcnt(8)" ::: "memory");      // tile ts+2 landed
        __builtin_amdgcn_s_barrier();
    }
    compute_step(As[0], Bs[0], acc, wr, wc, colB, kq);       // tile 14
    __builtin_amdgcn_s_barrier();
    asm volatile("s_waitcnt vmcnt(0)" ::: "memory");          // tile 15 landed
    __builtin_amdgcn_s_barrier();
    compute_step(As[1], Bs[1], acc, wr, wc, colB, kq);       // tile 15

    // fused loss epilogue: ti = wr*64+m*16+kq*4+j, tj = wc*64+n*16+colB
    float lsum = 0.f;
#pragma unroll
    for (int m = 0; m < 4; ++m) {
#pragma unroll
        for (int n = 0; n < 4; ++n) {
#pragma unroll
            for (int j = 0; j < 4; ++j) {
                int ti = wr * 64 + m * 16 + kq * 4 + j;
                int tj = wc * 64 + n * 16 + colB;
                int gi = rowA + ti, gj = rowB + tj;
                if (gi > gj) {
                    float c = acc[m][n][j] * FSCALE2_INV;
                    float v = (labI[ti] == labJ[tj]) ? fmaxf(2.0f - c, 0.0f) : c;
                    lsum += v * v;
                }
            }
        }
    }
#pragma unroll
    for (int off = 32; off > 0; off >>= 1) lsum += __shfl_down(lsum, off);
    if (lane == 0) red[wv] = lsum;
    __syncthreads();
    if (tid == 0) partials[blockIdx.x] = red[0] + red[1] + red[2] + red[3];
}

// ---------------- Kernel 3: deterministic final reduction -----------------
__global__ __launch_bounds__(256) void finalize(
    const float* __restrict__ partials, float* __restrict__ out) {
    float s = 0.f;
    for (int i = threadIdx.x; i < NJOBS; i += 256) s += partials[i];
#pragma unroll
    for (int off = 32; off > 0; off >>= 1) s += __shfl_down(s, off);
    __shared__ float red[4];
    int lane = threadIdx.x & 63, wv = threadIdx.x >> 6;
    if (lane == 0) red[wv] = s;
    __syncthreads();
    if (threadIdx.x == 0) {
        const double npair = (double)ROWS * (ROWS - 1) / 2.0;
        out[0] = (float)((double)(red[0] + red[1] + red[2] + red[3]) / npair);
    }
}

extern "C" void kernel_launch(void* const* d_in, const int* in_sizes, int n_in,
                              void* d_out, int out_size, void* d_ws, size_t ws_size,
                              hipStream_t stream) {
    const float* ys = (const float*)d_in[0];
    const int* labels = (const int*)d_in[1];
    float* out = (float*)d_out;

    unsigned char* yn = (unsigned char*)d_ws;                        // 8 MB fp8
    float* partials = (float*)((char*)d_ws + (size_t)ROWS * KDIM);   // 2.1 KB

    normalize_rows<<<ROWS, 256, 0, stream>>>(ys, (unsigned int*)yn);
    gram_loss<<<NJOBS, 256, 0, stream>>>(yn, labels, partials);
    finalize<<<1, 256, 0, stream>>>(partials, out);
}

// Round 11
// 46.633 us; speedup vs baseline: 4.9228x; 1.0893x over previous
//
#include <hip/hip_runtime.h>

// ContrastiveLoss: ys [4096,2048] f32, labels [4096] i32 -> scalar f32
// loss = mean over strict lower triangle of: same ? relu(2-cos)^2 : cos^2
// cos = pairwise cosine similarity of rows of ys (norm clamped at 1e-6).
//
// Round-11: best-of-both. r6 geometry (128x64 tiles, 1056 blocks, 4 waves
// of 64x32 -- the measured-best TLP point) + r10's counted-vmcnt double-
// buffer schedule (raw s_barrier, s_waitcnt vmcnt(6), unroll 1, flat
// per-wave stage pointers -- never vmcnt(0) in the main loop). fp8
// staging, MX-scaled K=128 MFMA, XOR swizzle.

#define ROWS 4096
#define KDIM 2048
// 128-row x 64-col tiles over the lower triangle: bi in [0,32), bj in
// [0,64); keep bj <= 2*bi+1 -> sum(2bi+2) = 1056 jobs.
#define NJOBS 1056
#define BK 128              // k-elements (= bytes) per K-step
#define NSTEPS (KDIM / BK)  // 16
#define FSCALE 32.0f        // fp8 pre-scale
#define FSCALE2_INV (1.0f / (FSCALE * FSCALE))
#define SCALE_ONE 0x7F7F7F7F  // E8M0 exponent 127 -> 2^0 in every byte

typedef float f32x4 __attribute__((ext_vector_type(4)));
typedef int i32x4 __attribute__((ext_vector_type(4)));
typedef int i32x8 __attribute__((ext_vector_type(8)));

__device__ __forceinline__ void async_copy16(const unsigned char* g, unsigned char* l) {
    __builtin_amdgcn_global_load_lds(
        (const __attribute__((address_space(1))) void*)g,
        (__attribute__((address_space(3))) void*)l,
        16, 0, 0);
}

// ---------------- Kernel 1: row normalize, f32 -> fp8 e4m3 (x32) ----------
__global__ __launch_bounds__(256) void normalize_rows(
    const float* __restrict__ ys, unsigned int* __restrict__ yn) {
    int row = blockIdx.x;
    const float4* src = (const float4*)(ys + (size_t)row * KDIM);
    float4 vals[2];
    float ss = 0.f;
#pragma unroll
    for (int i = 0; i < 2; ++i) {
        float4 v = src[threadIdx.x + i * 256];
        vals[i] = v;
        ss += v.x * v.x + v.y * v.y + v.z * v.z + v.w * v.w;
    }
#pragma unroll
    for (int off = 32; off > 0; off >>= 1) ss += __shfl_down(ss, off);
    __shared__ float red[4];
    int lane = threadIdx.x & 63, wv = threadIdx.x >> 6;
    if (lane == 0) red[wv] = ss;
    __syncthreads();
    float tot = red[0] + red[1] + red[2] + red[3];
    float inv = FSCALE / fmaxf(sqrtf(tot), 1e-6f);
    unsigned int* dst = yn + (size_t)row * (KDIM / 4);
#pragma unroll
    for (int i = 0; i < 2; ++i) {
        float4 v = vals[i];
        int p = __builtin_amdgcn_cvt_pk_fp8_f32(v.x * inv, v.y * inv, 0, false);
        p = __builtin_amdgcn_cvt_pk_fp8_f32(v.z * inv, v.w * inv, p, true);
        dst[threadIdx.x + i * 256] = (unsigned int)p;
    }
}

// ---------------- Kernel 2: 128x64 Gram tile + fused loss -----------------
// Per-wave staging: wave wv covers A chunks {wv, wv+4, wv+8, wv+12} (rows
// wv*8 + it*32 + srow) and B chunks {16+wv, 20+wv} (rows wv*8 + it*32 +
// srow). 6 global_load_lds per wave per tile -> vmcnt granularity 6.
__device__ __forceinline__ void stage_tile(
    const unsigned char* pA, const unsigned char* pB, int k0,
    unsigned char* As, unsigned char* Bs, int wv) {
#pragma unroll
    for (int it = 0; it < 4; ++it)
        async_copy16(pA + (size_t)it * 32 * KDIM + k0, As + (it * 4 + wv) * 1024);
#pragma unroll
    for (int it = 0; it < 2; ++it)
        async_copy16(pB + (size_t)it * 32 * KDIM + k0, Bs + (it * 4 + wv) * 1024);
}

__device__ __forceinline__ void compute_step(
    const unsigned char* As, const unsigned char* Bs,
    f32x4 acc[4][2], int wr, int wc, int colB, int kq) {
    // Lane kq's 32 true-k bytes sit at granules 2kq, 2kq+1; staging's
    // inverse-XOR means addr0 and addr0^16 give ascending k order.
    i32x8 af8[4];
#pragma unroll
    for (int m = 0; m < 4; ++m) {
        int row = wr * 64 + m * 16 + colB;
        int byte0 = (row * BK + kq * 32) ^ ((row & 7) << 4);
        i32x4 lo = *(const i32x4*)(As + byte0);
        i32x4 hi = *(const i32x4*)(As + (byte0 ^ 16));
        af8[m] = (i32x8){lo.x, lo.y, lo.z, lo.w, hi.x, hi.y, hi.z, hi.w};
    }
#pragma unroll
    for (int n = 0; n < 2; ++n) {
        int row = wc * 32 + n * 16 + colB;
        int byte0 = (row * BK + kq * 32) ^ ((row & 7) << 4);
        i32x4 lo = *(const i32x4*)(Bs + byte0);
        i32x4 hi = *(const i32x4*)(Bs + (byte0 ^ 16));
        i32x8 bn = (i32x8){lo.x, lo.y, lo.z, lo.w, hi.x, hi.y, hi.z, hi.w};
#pragma unroll
        for (int m = 0; m < 4; ++m)
            acc[m][n] = __builtin_amdgcn_mfma_scale_f32_16x16x128_f8f6f4(
                af8[m], bn, acc[m][n],
                0, 0,                  // cbsz=fp8, blgp=fp8
                0, SCALE_ONE,          // opsel_a, scale_a (1.0)
                0, SCALE_ONE);         // opsel_b, scale_b (1.0)
    }
}

__global__ __launch_bounds__(256) void gram_loss(
    const unsigned char* __restrict__ yn, const int* __restrict__ labels,
    float* __restrict__ partials) {
    // XCD-chunk swizzle (bijective: 1056 % 8 == 0, 132 jobs per XCD):
    int t = (blockIdx.x & 7) * (NJOBS / 8) + (blockIdx.x >> 3);
    // job t -> (bi, bj): jobs for bi occupy [bi*(bi+1), bi*(bi+1)+2bi+2)
    int bi = (int)((sqrtf((float)(4 * t + 1)) - 1.0f) * 0.5f);
    while (bi * (bi + 1) > t) --bi;
    while ((bi + 1) * (bi + 2) <= t) ++bi;
    int bj = t - bi * (bi + 1);

    __shared__ __attribute__((aligned(16))) unsigned char As[2][128 * BK];  // 2x16KB
    __shared__ __attribute__((aligned(16))) unsigned char Bs[2][64 * BK];   // 2x8KB
    __shared__ int labI[128];
    __shared__ int labJ[64];
    __shared__ float red[4];

    int tid = threadIdx.x, lane = tid & 63, wv = tid >> 6;
    int wr = wv >> 1, wc = wv & 1;
    int rowA = bi * 128, rowB = bj * 64;

    if (tid < 128) labI[tid] = labels[rowA + tid];
    else if (tid < 192) labJ[tid - 128] = labels[rowB + tid - 128];

    // staging: lane covers row lane>>3; 16B granule (lane&7) pre-XORed with
    // row so linear global_load_lds writes land swizzled: byte^=((row&7)<<4).
    int srow = lane >> 3;
    int sbyte = ((lane & 7) ^ srow) * 16;
    const unsigned char* pA = yn + (size_t)(rowA + wv * 8 + srow) * KDIM + sbyte;
    const unsigned char* pB = yn + (size_t)(rowB + wv * 8 + srow) * KDIM + sbyte;

    f32x4 zero = {0.f, 0.f, 0.f, 0.f};
    f32x4 acc[4][2];
#pragma unroll
    for (int m = 0; m < 4; ++m)
#pragma unroll
        for (int n = 0; n < 2; ++n) acc[m][n] = zero;

    int colB = lane & 15;  // spatial index within 16x16 fragment
    int kq = lane >> 4;    // k-quarter: lane holds k = 32*kq .. +31

    // ---- counted-vmcnt double-buffer pipeline (16 K-steps) ----
    stage_tile(pA, pB, 0 * BK, As[0], Bs[0], wv);
    stage_tile(pA, pB, 1 * BK, As[1], Bs[1], wv);
    asm volatile("s_waitcnt vmcnt(6) lgkmcnt(0)" ::: "memory");  // tile0 + labels
    __builtin_amdgcn_s_barrier();

#pragma unroll 1
    for (int ts = 0; ts < NSTEPS - 2; ts += 2) {
        compute_step(As[0], Bs[0], acc, wr, wc, colB, kq);   // tile ts
        __builtin_amdgcn_s_barrier();                         // buf0 free
        stage_tile(pA, pB, (ts + 2) * BK, As[0], Bs[0], wv);
        asm volatile("s_waitcnt vmcnt(6)" ::: "memory");      // tile ts+1 landed
        __builtin_amdgcn_s_barrier();

        compute_step(As[1], Bs[1], acc, wr, wc, colB, kq);   // tile ts+1
        __builtin_amdgcn_s_barrier();                         // buf1 free
        stage_tile(pA, pB, (ts + 3) * BK, As[1], Bs[1], wv);
        asm volatile("s_waitcnt vmcnt(6)" ::: "memory");      // tile ts+2 landed
        __builtin_amdgcn_s_barrier();
    }
    compute_step(As[0], Bs[0], acc, wr, wc, colB, kq);       // tile 14
    __builtin_amdgcn_s_barrier();
    asm volatile("s_waitcnt vmcnt(0)" ::: "memory");          // tile 15 landed
    __builtin_amdgcn_s_barrier();
    compute_step(As[1], Bs[1], acc, wr, wc, colB, kq);       // tile 15

    // fused loss epilogue: ti = wr*64+m*16+kq*4+j, tj = wc*32+n*16+colB
    float lsum = 0.f;
#pragma unroll
    for (int m = 0; m < 4; ++m) {
#pragma unroll
        for (int n = 0; n < 2; ++n) {
#pragma unroll
            for (int j = 0; j < 4; ++j) {
                int ti = wr * 64 + m * 16 + kq * 4 + j;
                int tj = wc * 32 + n * 16 + colB;
                int gi = rowA + ti, gj = rowB + tj;
                if (gi > gj) {
                    float c = acc[m][n][j] * FSCALE2_INV;
                    float v = (labI[ti] == labJ[tj]) ? fmaxf(2.0f - c, 0.0f) : c;
                    lsum += v * v;
                }
            }
        }
    }
#pragma unroll
    for (int off = 32; off > 0; off >>= 1) lsum += __shfl_down(lsum, off);
    if (lane == 0) red[wv] = lsum;
    __syncthreads();
    if (tid == 0) partials[blockIdx.x] = red[0] + red[1] + red[2] + red[3];
}

// ---------------- Kernel 3: deterministic final reduction -----------------
__global__ __launch_bounds__(256) void finalize(
    const float* __restrict__ partials, float* __restrict__ out) {
    float s = 0.f;
    for (int i = threadIdx.x; i < NJOBS; i += 256) s += partials[i];
#pragma unroll
    for (int off = 32; off > 0; off >>= 1) s += __shfl_down(s, off);
    __shared__ float red[4];
    int lane = threadIdx.x & 63, wv = threadIdx.x >> 6;
    if (lane == 0) red[wv] = s;
    __syncthreads();
    if (threadIdx.x == 0) {
        const double npair = (double)ROWS * (ROWS - 1) / 2.0;
        out[0] = (float)((double)(red[0] + red[1] + red[2] + red[3]) / npair);
    }
}

extern "C" void kernel_launch(void* const* d_in, const int* in_sizes, int n_in,
                              void* d_out, int out_size, void* d_ws, size_t ws_size,
                              hipStream_t stream) {
    const float* ys = (const float*)d_in[0];
    const int* labels = (const int*)d_in[1];
    float* out = (float*)d_out;

    unsigned char* yn = (unsigned char*)d_ws;                        // 8 MB fp8
    float* partials = (float*)((char*)d_ws + (size_t)ROWS * KDIM);   // 4.2 KB

    normalize_rows<<<ROWS, 256, 0, stream>>>(ys, (unsigned int*)yn);
    gram_loss<<<NJOBS, 256, 0, stream>>>(yn, labels, partials);
    finalize<<<1, 256, 0, stream>>>(partials, out);
}